// Round 13
// baseline (378.820 us; speedup 1.0000x reference)
//
#include <hip/hip_runtime.h>

#define N_NODES 100000
#define HALFN 50000
#define IN_DIM 128
#define HID 64
#define OUT_DIM 5
#define N_EDGES 3200000

#define BSHIFT 7
#define BROWS 128  // nodes per bucket
#define NBUCK ((N_NODES + BROWS - 1) / BROWS)  // 782
#define FILLB_CHUNK 16384
#define NBF ((N_EDGES + FILLB_CHUNK - 1) / FILLB_CHUNK)  // 196

typedef __attribute__((ext_vector_type(8))) short short8;
typedef __attribute__((ext_vector_type(8))) unsigned short ushort8_t;
typedef __attribute__((ext_vector_type(4))) float f32x4;
typedef __attribute__((ext_vector_type(2))) float f32x2_t;
typedef unsigned short ushort_t;
typedef unsigned int uint_t;
typedef unsigned char uchar_t;

static __device__ inline ushort_t f2bf(float f) {
  union { float f; uint_t u; } v; v.f = f;
  const uint_t r = v.u + 0x7FFFu + ((v.u >> 16) & 1u);  // RNE
  return (ushort_t)(r >> 16);
}
static __device__ inline uint_t pack2(float a, float b) {
  return (uint_t)f2bf(a) | ((uint_t)f2bf(b) << 16);
}
static __device__ inline float bf2f(ushort_t u) {
  return __uint_as_float((uint_t)u << 16);
}
// 4 fp8(e4m3) bytes -> accumulate into 4 f32 (HW cvt, 2 per instr)
static __device__ inline void fp8x4_acc(uint_t w, float& c0, float& c1, float& c2,
                                        float& c3) {
  const f32x2_t lo = __builtin_amdgcn_cvt_pk_f32_fp8((int)w, false);
  const f32x2_t hi = __builtin_amdgcn_cvt_pk_f32_fp8((int)w, true);
  c0 += lo[0];
  c1 += lo[1];
  c2 += hi[0];
  c3 += hi[1];
}
static __device__ inline uchar_t f2fp8(float f) {
  return (uchar_t)__builtin_amdgcn_cvt_pk_fp8_f32(f, 0.0f, 0, false);
}

// ---- sort phase A: per-chunk 782-bucket histogram, plain stores (no atomics) ----
__global__ __launch_bounds__(256) void histA_k(const int* __restrict__ dst,
                                               int* __restrict__ H) {
  __shared__ int hist[NBUCK];
  const int t = threadIdx.x;
  const int b = blockIdx.x;
  const int e0 = b * FILLB_CHUNK;
  const int e1 = min(e0 + FILLB_CHUNK, N_EDGES);
  for (int i = t; i < NBUCK; i += 256) hist[i] = 0;
  __syncthreads();
  for (int e = e0 + t; e < e1; e += 256) atomicAdd(&hist[dst[e] >> BSHIFT], 1);
  __syncthreads();
  for (int c = t; c < NBUCK; c += 256) H[(size_t)c * NBF + b] = hist[c];
}

// ---- sort phase A2: per-bucket scan over chunks -> per-(chunk,bucket) bases ----
__global__ __launch_bounds__(256) void colscan_k(const int* __restrict__ H,
                                                 int* __restrict__ P,
                                                 int* __restrict__ bcount) {
  const int lane = threadIdx.x & 63;
  const int wv = threadIdx.x >> 6;
  const int c = blockIdx.x * 4 + wv;
  if (c >= NBUCK) return;
  const int* col = H + (size_t)c * NBF;
  int* pcol = P + (size_t)c * NBF;
  int carry = 0;
#pragma unroll
  for (int k = 0; k < (NBF + 63) / 64; ++k) {
    const int idx = k * 64 + lane;
    const int v = (idx < NBF) ? col[idx] : 0;
    int s = v;
#pragma unroll
    for (int off = 1; off < 64; off <<= 1) {
      const int x = __shfl_up(s, off);
      if (lane >= off) s += x;
    }
    if (idx < NBF) pcol[idx] = carry + s - v;  // exclusive prefix
    carry += __shfl(s, 63);
  }
  if (lane == 0) bcount[c] = carry;
}

// ---- scan: boff[783] (bucket offsets) + noff sentinel ----
__global__ __launch_bounds__(256) void bscan_k(const int* __restrict__ bcount,
                                               int* __restrict__ boff,
                                               int* __restrict__ noff) {
  __shared__ int pref[NBUCK + 1];
  __shared__ int tsum[256];
  const int t = threadIdx.x;
  int v[4];
  int s = 0;
#pragma unroll
  for (int j = 0; j < 4; ++j) {
    const int idx = t * 4 + j;
    v[j] = (idx < NBUCK) ? bcount[idx] : 0;
    s += v[j];
  }
  tsum[t] = s;
  __syncthreads();
  for (int off = 1; off < 256; off <<= 1) {
    int x = (t >= off) ? tsum[t - off] : 0;
    __syncthreads();
    tsum[t] += x;
    __syncthreads();
  }
  int pre = tsum[t] - s;
#pragma unroll
  for (int j = 0; j < 4; ++j) {
    const int idx = t * 4 + j;
    if (idx < NBUCK) pref[idx] = pre;
    pre += v[j];
  }
  if (t == 0) pref[NBUCK] = N_EDGES;
  __syncthreads();
  for (int i = t; i <= NBUCK; i += 256) boff[i] = pref[i];
  if (t == 0) noff[N_NODES] = N_EDGES;
}

// ---- sort phase B: deterministic bucket fill (block-local atomics only) ----
__global__ __launch_bounds__(256) void fillD_k(const int* __restrict__ src,
                                               const int* __restrict__ dst,
                                               const int* __restrict__ boff,
                                               const int* __restrict__ P,
                                               int* __restrict__ bedge) {
  __shared__ int base[NBUCK];
  __shared__ int cur[NBUCK];
  const int t = threadIdx.x;
  const int b = blockIdx.x;
  const int e0 = b * FILLB_CHUNK;
  const int e1 = min(e0 + FILLB_CHUNK, N_EDGES);
  for (int c = t; c < NBUCK; c += 256) {
    base[c] = boff[c] + P[(size_t)c * NBF + b];
    cur[c] = 0;
  }
  __syncthreads();
  for (int e = e0 + t; e < e1; e += 256) {
    const int d = dst[e];
    const int c = d >> BSHIFT;
    const int pos = base[c] + atomicAdd(&cur[c], 1);
    bedge[pos] = (src[e] << BSHIFT) | (d & (BROWS - 1));
  }
}

// ---- bucket -> full CSR, 256-bin: key = (dstLow<<1) | (src >= HALFN) ----
// Per node: edges with src<HALFN first (noff..nsplit), then src>=HALFN (..noff+1).
__global__ __launch_bounds__(256) void csrfill_k(const int* __restrict__ boff,
                                                 const int* __restrict__ bedge,
                                                 int* __restrict__ csr,
                                                 int* __restrict__ noff,
                                                 int* __restrict__ nsplit) {
  __shared__ int hist[256];
  __shared__ int sc[256];
  __shared__ int cur[256];
  const int t = threadIdx.x;
  const int b = blockIdx.x;
  const int e0 = boff[b];
  const int e1 = boff[b + 1];
  hist[t] = 0;
  cur[t] = 0;
  __syncthreads();
  for (int e = e0 + t; e < e1; e += 256) {
    const int p = bedge[e];
    const int key = ((p & (BROWS - 1)) << 1) | ((p >> BSHIFT) >= HALFN ? 1 : 0);
    atomicAdd(&hist[key], 1);
  }
  __syncthreads();
  sc[t] = hist[t];
  __syncthreads();
  for (int off = 1; off < 256; off <<= 1) {
    int x = (t >= off) ? sc[t - off] : 0;
    __syncthreads();
    sc[t] += x;
    __syncthreads();
  }
  sc[t] -= hist[t];  // exclusive
  __syncthreads();
  if (t < BROWS) {
    const int node = b * BROWS + t;
    if (node < N_NODES) {
      noff[node] = e0 + sc[2 * t];
      nsplit[node] = e0 + sc[2 * t + 1];
    }
  }
  __syncthreads();
  for (int e = e0 + t; e < e1; e += 256) {
    const int p = bedge[e];
    const int key = ((p & (BROWS - 1)) << 1) | ((p >> BSHIFT) >= HALFN ? 1 : 0);
    const int pos = e0 + sc[key] + atomicAdd(&cur[key], 1);
    csr[pos] = p >> BSHIFT;
  }
}

// ---- MFMA dual GEMM: Y8 = fp8(X @ Wl^T), Zb = bf16(X @ Wr^T) ----
template <int K, bool BF16IN>
__global__ __launch_bounds__(256) void gemm_mfma(const void* __restrict__ Xv,
                                                 const float* __restrict__ Wl,
                                                 const float* __restrict__ Wr,
                                                 uchar_t* __restrict__ Y8,
                                                 ushort_t* __restrict__ Zb, int n) {
  __shared__ uint4 ldsq[(256 * K * 2) / 16];  // 128 X-rows + 2*64 W-rows, bf16
  char* xlds = (char*)ldsq;
  char* wlds = xlds + 128 * K * 2;
  const int t = threadIdx.x;
  const int lane = t & 63;
  const int wv = t >> 6;
  const int rowBase = blockIdx.x * 128;
  const int K2 = K * 2;
  const int KC = K / 8;  // 16B chunks per row

  // stage X (swizzled)
  for (int c = t; c < 128 * KC; c += 256) {
    const int r = c / KC, k8 = c - r * KC;
    const int row = rowBase + r;
    uint4 w = {0u, 0u, 0u, 0u};
    if (row < n) {
      if (BF16IN) {
        w = ((const uint4*)((const ushort_t*)Xv + (size_t)row * K))[k8];
      } else {
        const float4* p = (const float4*)((const float*)Xv + (size_t)row * K + k8 * 8);
        const float4 f0 = p[0];
        const float4 f1 = p[1];
        w.x = pack2(f0.x, f0.y);
        w.y = pack2(f0.z, f0.w);
        w.z = pack2(f1.x, f1.y);
        w.w = pack2(f1.z, f1.w);
      }
    }
    const int byte = (r * K2 + k8 * 16) ^ ((r & 7) << 4);
    *(uint4*)(xlds + byte) = w;
  }
  // stage Wl, Wr (f32 -> bf16)
  for (int c = t; c < 2 * 64 * KC; c += 256) {
    const int m = c / (64 * KC);
    const int c2 = c - m * 64 * KC;
    const int r = c2 / KC, k8 = c2 - r * KC;
    const float4* p = (const float4*)((m ? Wr : Wl) + (size_t)r * K + k8 * 8);
    const float4 f0 = p[0];
    const float4 f1 = p[1];
    uint4 w;
    w.x = pack2(f0.x, f0.y);
    w.y = pack2(f0.z, f0.w);
    w.z = pack2(f1.x, f1.y);
    w.w = pack2(f1.z, f1.w);
    const int byte = (m * 64 * K2) + ((r * K2 + k8 * 16) ^ ((r & 7) << 4));
    *(uint4*)(wlds + byte) = w;
  }
  __syncthreads();

  f32x4 accY[2][4], accZ[2][4];
#pragma unroll
  for (int rt = 0; rt < 2; ++rt)
#pragma unroll
    for (int ct = 0; ct < 4; ++ct) {
      accY[rt][ct] = (f32x4){0.f, 0.f, 0.f, 0.f};
      accZ[rt][ct] = (f32x4){0.f, 0.f, 0.f, 0.f};
    }

  const int fr = lane & 15;
  const int kg = lane >> 4;
#pragma unroll
  for (int kk = 0; kk < K / 32; ++kk) {
    const int kbyte = kk * 64 + kg * 16;
    short8 a[2];
#pragma unroll
    for (int rt = 0; rt < 2; ++rt) {
      const int r = wv * 32 + rt * 16 + fr;
      a[rt] = *(const short8*)(xlds + ((r * K2 + kbyte) ^ ((r & 7) << 4)));
    }
#pragma unroll
    for (int ct = 0; ct < 4; ++ct) {
      const int wr = ct * 16 + fr;
      const int byteY = (wr * K2 + kbyte) ^ ((wr & 7) << 4);
      const short8 bY = *(const short8*)(wlds + byteY);
      const short8 bZ = *(const short8*)(wlds + byteY + 64 * K2);
#pragma unroll
      for (int rt = 0; rt < 2; ++rt) {
        accY[rt][ct] =
            __builtin_amdgcn_mfma_f32_16x16x32_bf16(a[rt], bY, accY[rt][ct], 0, 0, 0);
        accZ[rt][ct] =
            __builtin_amdgcn_mfma_f32_16x16x32_bf16(a[rt], bZ, accZ[rt][ct], 0, 0, 0);
      }
    }
  }

  // epilogue: D row=(lane>>4)*4+q, col=lane&15  [m89-verified]
#pragma unroll
  for (int rt = 0; rt < 2; ++rt) {
#pragma unroll
    for (int q = 0; q < 4; ++q) {
      const int row = rowBase + wv * 32 + rt * 16 + kg * 4 + q;
      if (row < n) {
#pragma unroll
        for (int ct = 0; ct < 4; ++ct) {
          const int col = ct * 16 + fr;
          Y8[(size_t)row * 64 + col] = f2fp8(accY[rt][ct][q]);
          Zb[(size_t)row * 64 + col] = f2bf(accZ[rt][ct][q]);
        }
      }
    }
  }
}

// ---- half-gather: PHASE 0 reads y8 rows [0,HALFN) (3.2MB, L2-resident),
// writes bf16 partials; PHASE 1 reads rows [HALFN,N), adds partials, epilogue.
// All streaming accesses (csr/noff/Zb/partials/outputs) are nontemporal so the
// resident table half is not evicted.
template <int PHASE, bool FINAL>
__global__ __launch_bounds__(256) void gather_k(
    const int* __restrict__ noff, const int* __restrict__ nsplit,
    const int* __restrict__ csr, const uchar_t* __restrict__ Y8,
    const ushort_t* __restrict__ Zb, const float* __restrict__ bias,
    const float* __restrict__ Wh, const float* __restrict__ bh,
    ushort_t* __restrict__ Pacc, ushort_t* __restrict__ Hb,
    float* __restrict__ Hf, float* __restrict__ logits, int n) {
  const int lane = threadIdx.x & 63;
  const int g = lane >> 3;  // edge stream 0..7
  const int r = lane & 7;   // channel slot: channels r*8 .. r*8+7
  const int wid = (blockIdx.x * blockDim.x + threadIdx.x) >> 6;
  const int nw = (gridDim.x * blockDim.x) >> 6;
  float4 biasA = {0, 0, 0, 0}, biasB = {0, 0, 0, 0};
  if (PHASE == 1) {
    biasA = ((const float4*)bias)[2 * r];
    biasB = ((const float4*)bias)[2 * r + 1];
  }
  float4 whA[5], whB[5];
  if (FINAL) {
#pragma unroll
    for (int o = 0; o < 5; ++o) {
      whA[o] = ((const float4*)(Wh + o * 64))[2 * r];
      whB[o] = ((const float4*)(Wh + o * 64))[2 * r + 1];
    }
  }

  for (int row = wid; row < n; row += nw) {
    int e0, e1, ne = 0;
    if (PHASE == 0) {
      e0 = __builtin_nontemporal_load(noff + row);
      e1 = __builtin_nontemporal_load(nsplit + row);
    } else {
      const int n0 = __builtin_nontemporal_load(noff + row);
      e0 = __builtin_nontemporal_load(nsplit + row);
      e1 = __builtin_nontemporal_load(noff + row + 1);
      ne = e1 - n0;
    }
    float a0 = 0.f, a1 = 0.f, a2 = 0.f, a3 = 0.f;
    float a4 = 0.f, a5 = 0.f, a6 = 0.f, a7 = 0.f;
    for (int eb = e0; eb < e1; eb += 64) {
      const int eidx = eb + 8 * r + g;  // lane g*8+j holds edge eb+8j+g
      const int sidx =
          (eidx < e1) ? __builtin_nontemporal_load(csr + eidx) : N_NODES;
      const int msteps = min(8, (e1 - eb + 7) >> 3);
      int j = 0;
      for (; j + 3 < msteps; j += 4) {
        const int s0 = __shfl(sidx, j, 8);
        const int s1 = __shfl(sidx, j + 1, 8);
        const int s2 = __shfl(sidx, j + 2, 8);
        const int s3 = __shfl(sidx, j + 3, 8);
        const uint2 v0 = *(const uint2*)(Y8 + (size_t)s0 * 64 + r * 8);
        const uint2 v1 = *(const uint2*)(Y8 + (size_t)s1 * 64 + r * 8);
        const uint2 v2 = *(const uint2*)(Y8 + (size_t)s2 * 64 + r * 8);
        const uint2 v3 = *(const uint2*)(Y8 + (size_t)s3 * 64 + r * 8);
        fp8x4_acc(v0.x, a0, a1, a2, a3);
        fp8x4_acc(v0.y, a4, a5, a6, a7);
        fp8x4_acc(v1.x, a0, a1, a2, a3);
        fp8x4_acc(v1.y, a4, a5, a6, a7);
        fp8x4_acc(v2.x, a0, a1, a2, a3);
        fp8x4_acc(v2.y, a4, a5, a6, a7);
        fp8x4_acc(v3.x, a0, a1, a2, a3);
        fp8x4_acc(v3.y, a4, a5, a6, a7);
      }
      for (; j < msteps; ++j) {
        const int s0 = __shfl(sidx, j, 8);
        const uint2 v0 = *(const uint2*)(Y8 + (size_t)s0 * 64 + r * 8);
        fp8x4_acc(v0.x, a0, a1, a2, a3);
        fp8x4_acc(v0.y, a4, a5, a6, a7);
      }
    }
    // combine the 8 edge-streams (xor over g bits: 8,16,32)
#pragma unroll
    for (int d = 8; d <= 32; d <<= 1) {
      a0 += __shfl_xor(a0, d);
      a1 += __shfl_xor(a1, d);
      a2 += __shfl_xor(a2, d);
      a3 += __shfl_xor(a3, d);
      a4 += __shfl_xor(a4, d);
      a5 += __shfl_xor(a5, d);
      a6 += __shfl_xor(a6, d);
      a7 += __shfl_xor(a7, d);
    }

    if (g == 0) {
      if (PHASE == 0) {
        ushort8_t pb;
        pb[0] = f2bf(a0); pb[1] = f2bf(a1); pb[2] = f2bf(a2); pb[3] = f2bf(a3);
        pb[4] = f2bf(a4); pb[5] = f2bf(a5); pb[6] = f2bf(a6); pb[7] = f2bf(a7);
        __builtin_nontemporal_store(pb, (ushort8_t*)(Pacc + (size_t)row * 64 + r * 8));
      } else {
        const ushort8_t pb = __builtin_nontemporal_load(
            (const ushort8_t*)(Pacc + (size_t)row * 64 + r * 8));
        a0 += bf2f(pb[0]); a1 += bf2f(pb[1]); a2 += bf2f(pb[2]); a3 += bf2f(pb[3]);
        a4 += bf2f(pb[4]); a5 += bf2f(pb[5]); a6 += bf2f(pb[6]); a7 += bf2f(pb[7]);
        const float inv = 1.0f / fmaxf((float)ne, 1.0f);
        const ushort8_t zv = __builtin_nontemporal_load(
            (const ushort8_t*)(Zb + (size_t)row * 64 + r * 8));
        const float h0 = fmaxf(fmaf(a0, inv, biasA.x + bf2f(zv[0])), 0.0f);
        const float h1 = fmaxf(fmaf(a1, inv, biasA.y + bf2f(zv[1])), 0.0f);
        const float h2 = fmaxf(fmaf(a2, inv, biasA.z + bf2f(zv[2])), 0.0f);
        const float h3 = fmaxf(fmaf(a3, inv, biasA.w + bf2f(zv[3])), 0.0f);
        const float h4 = fmaxf(fmaf(a4, inv, biasB.x + bf2f(zv[4])), 0.0f);
        const float h5 = fmaxf(fmaf(a5, inv, biasB.y + bf2f(zv[5])), 0.0f);
        const float h6 = fmaxf(fmaf(a6, inv, biasB.z + bf2f(zv[6])), 0.0f);
        const float h7 = fmaxf(fmaf(a7, inv, biasB.w + bf2f(zv[7])), 0.0f);
        if (!FINAL) {
          ushort8_t hb;
          hb[0] = f2bf(h0); hb[1] = f2bf(h1); hb[2] = f2bf(h2); hb[3] = f2bf(h3);
          hb[4] = f2bf(h4); hb[5] = f2bf(h5); hb[6] = f2bf(h6); hb[7] = f2bf(h7);
          __builtin_nontemporal_store(hb,
                                      (ushort8_t*)(Hb + (size_t)row * 64 + r * 8));
        } else {
          f32x4 hfA = {h0, h1, h2, h3};
          f32x4 hfB = {h4, h5, h6, h7};
          __builtin_nontemporal_store(hfA,
                                      (f32x4*)(Hf + (size_t)row * 64 + r * 8));
          __builtin_nontemporal_store(hfB,
                                      (f32x4*)(Hf + (size_t)row * 64 + r * 8 + 4));
          float q[5];
#pragma unroll
          for (int o = 0; o < 5; ++o) {
            q[o] = h0 * whA[o].x + h1 * whA[o].y + h2 * whA[o].z + h3 * whA[o].w +
                   h4 * whB[o].x + h5 * whB[o].y + h6 * whB[o].z + h7 * whB[o].w;
#pragma unroll
            for (int d = 1; d < 8; d <<= 1) q[o] += __shfl_xor(q[o], d, 8);
          }
          if (r == 0) {
#pragma unroll
            for (int o = 0; o < 5; ++o)
              __builtin_nontemporal_store(q[o] + bh[o], logits + (size_t)row * 5 + o);
          }
        }
      }
    }
  }
}

extern "C" void kernel_launch(void* const* d_in, const int* in_sizes, int n_in,
                              void* d_out, int out_size, void* d_ws, size_t ws_size,
                              hipStream_t stream) {
  const float* x = (const float*)d_in[0];
  const int* edge = (const int*)d_in[1];
  const float* W1l = (const float*)d_in[2];
  const float* b1l = (const float*)d_in[3];
  const float* W1r = (const float*)d_in[4];
  const float* W2l = (const float*)d_in[5];
  const float* b2l = (const float*)d_in[6];
  const float* W2r = (const float*)d_in[7];
  const float* Wh = (const float*)d_in[8];
  const float* bh = (const float*)d_in[9];
  const int* src = edge;
  const int* dst = edge + N_EDGES;

  float* out = (float*)d_out;
  float* logits = out;                            // [N,5]
  float* hout = out + (size_t)N_NODES * OUT_DIM;  // [N,64] f32

  const size_t N64 = (size_t)N_NODES * 64;
  ushort_t* zb = (ushort_t*)d_ws;          // [N,64] bf16
  ushort_t* h1b = zb + N64;                // [N,64] bf16
  ushort_t* pacc = h1b + N64;              // [N,64] bf16 partial sums
  uchar_t* y8 = (uchar_t*)(pacc + N64);    // [N+1,64] fp8 (row N = zeros)
  int* H = (int*)(y8 + N64 + 64);          // [NBUCK][NBF]
  int* P = H + (size_t)NBUCK * NBF;        // [NBUCK][NBF]
  int* bcount = P + (size_t)NBUCK * NBF;   // [NBUCK]
  int* boff = bcount + NBUCK;              // [NBUCK+1]
  int* bedge = boff + NBUCK + 1;           // [E]
  int* csr = bedge + N_EDGES;              // [E]
  int* noff = csr + N_EDGES;               // [N+1]
  int* nsplit = noff + N_NODES + 1;        // [N]

  // ---- CSR build: deterministic two-phase counting sort (no global atomics) ----
  hipMemsetAsync(y8 + N64, 0, 64, stream);  // zero sentinel row
  histA_k<<<NBF, 256, 0, stream>>>(dst, H);
  colscan_k<<<(NBUCK + 3) / 4, 256, 0, stream>>>(H, P, bcount);
  bscan_k<<<1, 256, 0, stream>>>(bcount, boff, noff);
  fillD_k<<<NBF, 256, 0, stream>>>(src, dst, boff, P, bedge);
  csrfill_k<<<NBUCK, 256, 0, stream>>>(boff, bedge, csr, noff, nsplit);

  const int mblocks = (N_NODES + 127) / 128;  // 782
  const int wblocks = 6250;                   // 25000 waves, ~4 rows each

  // ---- layer 1 ----
  gemm_mfma<IN_DIM, false><<<mblocks, 256, 0, stream>>>(x, W1l, W1r, y8, zb, N_NODES);
  gather_k<0, false><<<wblocks, 256, 0, stream>>>(noff, nsplit, csr, y8, nullptr,
                                                  nullptr, nullptr, nullptr, pacc,
                                                  nullptr, nullptr, nullptr, N_NODES);
  gather_k<1, false><<<wblocks, 256, 0, stream>>>(noff, nsplit, csr, y8, zb, b1l,
                                                  nullptr, nullptr, pacc, h1b,
                                                  nullptr, nullptr, N_NODES);

  // ---- layer 2 + head ----
  gemm_mfma<HID, true><<<mblocks, 256, 0, stream>>>(h1b, W2l, W2r, y8, zb, N_NODES);
  gather_k<0, false><<<wblocks, 256, 0, stream>>>(noff, nsplit, csr, y8, nullptr,
                                                  nullptr, nullptr, nullptr, pacc,
                                                  nullptr, nullptr, nullptr, N_NODES);
  gather_k<1, true><<<wblocks, 256, 0, stream>>>(noff, nsplit, csr, y8, zb, b2l, Wh,
                                                 bh, pacc, nullptr, hout, logits,
                                                 N_NODES);
}

// Round 14
// 237.764 us; speedup vs baseline: 1.5933x; 1.5933x over previous
//
#include <hip/hip_runtime.h>

#define N_NODES 100000
#define IN_DIM 128
#define HID 64
#define OUT_DIM 5
#define N_EDGES 3200000

#define BSHIFT 7
#define BROWS 128  // nodes per bucket
#define NBUCK ((N_NODES + BROWS - 1) / BROWS)  // 782
#define FILLB_CHUNK 16384
#define NBF ((N_EDGES + FILLB_CHUNK - 1) / FILLB_CHUNK)  // 196

typedef __attribute__((ext_vector_type(8))) short short8;
typedef __attribute__((ext_vector_type(4))) float f32x4;
typedef __attribute__((ext_vector_type(2))) float f32x2_t;
typedef unsigned short ushort_t;
typedef unsigned int uint_t;
typedef unsigned char uchar_t;

static __device__ inline ushort_t f2bf(float f) {
  union { float f; uint_t u; } v; v.f = f;
  const uint_t r = v.u + 0x7FFFu + ((v.u >> 16) & 1u);  // RNE
  return (ushort_t)(r >> 16);
}
static __device__ inline uint_t pack2(float a, float b) {
  return (uint_t)f2bf(a) | ((uint_t)f2bf(b) << 16);
}
static __device__ inline float bf2f(ushort_t u) {
  return __uint_as_float((uint_t)u << 16);
}
// 4 fp8(e4m3) bytes -> accumulate into 4 f32 (HW cvt, 2 per instr)
static __device__ inline void fp8x4_acc(uint_t w, float& c0, float& c1, float& c2,
                                        float& c3) {
  const f32x2_t lo = __builtin_amdgcn_cvt_pk_f32_fp8((int)w, false);
  const f32x2_t hi = __builtin_amdgcn_cvt_pk_f32_fp8((int)w, true);
  c0 += lo[0];
  c1 += lo[1];
  c2 += hi[0];
  c3 += hi[1];
}
static __device__ inline uchar_t f2fp8(float f) {
  return (uchar_t)__builtin_amdgcn_cvt_pk_fp8_f32(f, 0.0f, 0, false);
}

// ---- sort phase A: per-chunk 782-bucket histogram, plain stores (no atomics) ----
__global__ __launch_bounds__(256) void histA_k(const int* __restrict__ dst,
                                               int* __restrict__ H) {
  __shared__ int hist[NBUCK];
  const int t = threadIdx.x;
  const int b = blockIdx.x;
  const int e0 = b * FILLB_CHUNK;
  const int e1 = min(e0 + FILLB_CHUNK, N_EDGES);
  for (int i = t; i < NBUCK; i += 256) hist[i] = 0;
  __syncthreads();
  for (int e = e0 + t; e < e1; e += 256) atomicAdd(&hist[dst[e] >> BSHIFT], 1);
  __syncthreads();
  for (int c = t; c < NBUCK; c += 256) H[(size_t)c * NBF + b] = hist[c];
}

// ---- sort phase A2: per-bucket scan over chunks -> per-(chunk,bucket) bases ----
__global__ __launch_bounds__(256) void colscan_k(const int* __restrict__ H,
                                                 int* __restrict__ P,
                                                 int* __restrict__ bcount) {
  const int lane = threadIdx.x & 63;
  const int wv = threadIdx.x >> 6;
  const int c = blockIdx.x * 4 + wv;
  if (c >= NBUCK) return;
  const int* col = H + (size_t)c * NBF;
  int* pcol = P + (size_t)c * NBF;
  int carry = 0;
#pragma unroll
  for (int k = 0; k < (NBF + 63) / 64; ++k) {
    const int idx = k * 64 + lane;
    const int v = (idx < NBF) ? col[idx] : 0;
    int s = v;
#pragma unroll
    for (int off = 1; off < 64; off <<= 1) {
      const int x = __shfl_up(s, off);
      if (lane >= off) s += x;
    }
    if (idx < NBF) pcol[idx] = carry + s - v;  // exclusive prefix
    carry += __shfl(s, 63);
  }
  if (lane == 0) bcount[c] = carry;
}

// ---- scan: boff[783] (bucket offsets) + noff sentinel ----
__global__ __launch_bounds__(256) void bscan_k(const int* __restrict__ bcount,
                                               int* __restrict__ boff,
                                               int* __restrict__ noff) {
  __shared__ int pref[NBUCK + 1];
  __shared__ int tsum[256];
  const int t = threadIdx.x;
  int v[4];
  int s = 0;
#pragma unroll
  for (int j = 0; j < 4; ++j) {
    const int idx = t * 4 + j;
    v[j] = (idx < NBUCK) ? bcount[idx] : 0;
    s += v[j];
  }
  tsum[t] = s;
  __syncthreads();
  for (int off = 1; off < 256; off <<= 1) {
    int x = (t >= off) ? tsum[t - off] : 0;
    __syncthreads();
    tsum[t] += x;
    __syncthreads();
  }
  int pre = tsum[t] - s;
#pragma unroll
  for (int j = 0; j < 4; ++j) {
    const int idx = t * 4 + j;
    if (idx < NBUCK) pref[idx] = pre;
    pre += v[j];
  }
  if (t == 0) pref[NBUCK] = N_EDGES;
  __syncthreads();
  for (int i = t; i <= NBUCK; i += 256) boff[i] = pref[i];
  if (t == 0) noff[N_NODES] = N_EDGES;
}

// ---- sort phase B: deterministic bucket fill (block-local atomics only) ----
__global__ __launch_bounds__(256) void fillD_k(const int* __restrict__ src,
                                               const int* __restrict__ dst,
                                               const int* __restrict__ boff,
                                               const int* __restrict__ P,
                                               int* __restrict__ bedge) {
  __shared__ int base[NBUCK];
  __shared__ int cur[NBUCK];
  const int t = threadIdx.x;
  const int b = blockIdx.x;
  const int e0 = b * FILLB_CHUNK;
  const int e1 = min(e0 + FILLB_CHUNK, N_EDGES);
  for (int c = t; c < NBUCK; c += 256) {
    base[c] = boff[c] + P[(size_t)c * NBF + b];
    cur[c] = 0;
  }
  __syncthreads();
  for (int e = e0 + t; e < e1; e += 256) {
    const int d = dst[e];
    const int c = d >> BSHIFT;
    const int pos = base[c] + atomicAdd(&cur[c], 1);
    bedge[pos] = (src[e] << BSHIFT) | (d & (BROWS - 1));
  }
}

// ---- bucket -> full CSR: block per bucket, LDS counting sort ----
__global__ __launch_bounds__(256) void csrfill_k(const int* __restrict__ boff,
                                                 const int* __restrict__ bedge,
                                                 int* __restrict__ csr,
                                                 int* __restrict__ noff) {
  __shared__ int hist[BROWS];
  __shared__ int sc[BROWS];
  __shared__ int cur[BROWS];
  const int t = threadIdx.x;
  const int b = blockIdx.x;
  const int e0 = boff[b];
  const int e1 = boff[b + 1];
  if (t < BROWS) {
    hist[t] = 0;
    cur[t] = 0;
  }
  __syncthreads();
  for (int e = e0 + t; e < e1; e += 256) atomicAdd(&hist[bedge[e] & (BROWS - 1)], 1);
  __syncthreads();
  if (t < BROWS) sc[t] = hist[t];
  __syncthreads();
  for (int off = 1; off < BROWS; off <<= 1) {
    int x = (t >= off && t < BROWS) ? sc[t - off] : 0;
    __syncthreads();
    if (t < BROWS) sc[t] += x;
    __syncthreads();
  }
  if (t < BROWS) {
    const int node = b * BROWS + t;
    if (node < N_NODES) noff[node] = e0 + sc[t] - hist[t];
    sc[t] -= hist[t];
  }
  __syncthreads();
  for (int e = e0 + t; e < e1; e += 256) {
    const int p = bedge[e];
    const int d = p & (BROWS - 1);
    const int pos = e0 + sc[d] + atomicAdd(&cur[d], 1);
    csr[pos] = p >> BSHIFT;
  }
}

// ---- MFMA dual GEMM: Y8 = fp8(X @ Wl^T), Zb = bf16(X @ Wr^T) ----
template <int K, bool BF16IN>
__global__ __launch_bounds__(256) void gemm_mfma(const void* __restrict__ Xv,
                                                 const float* __restrict__ Wl,
                                                 const float* __restrict__ Wr,
                                                 uchar_t* __restrict__ Y8,
                                                 ushort_t* __restrict__ Zb, int n) {
  __shared__ uint4 ldsq[(256 * K * 2) / 16];  // 128 X-rows + 2*64 W-rows, bf16
  char* xlds = (char*)ldsq;
  char* wlds = xlds + 128 * K * 2;
  const int t = threadIdx.x;
  const int lane = t & 63;
  const int wv = t >> 6;
  const int rowBase = blockIdx.x * 128;
  const int K2 = K * 2;
  const int KC = K / 8;  // 16B chunks per row

  // stage X (swizzled)
  for (int c = t; c < 128 * KC; c += 256) {
    const int r = c / KC, k8 = c - r * KC;
    const int row = rowBase + r;
    uint4 w = {0u, 0u, 0u, 0u};
    if (row < n) {
      if (BF16IN) {
        w = ((const uint4*)((const ushort_t*)Xv + (size_t)row * K))[k8];
      } else {
        const float4* p = (const float4*)((const float*)Xv + (size_t)row * K + k8 * 8);
        const float4 f0 = p[0];
        const float4 f1 = p[1];
        w.x = pack2(f0.x, f0.y);
        w.y = pack2(f0.z, f0.w);
        w.z = pack2(f1.x, f1.y);
        w.w = pack2(f1.z, f1.w);
      }
    }
    const int byte = (r * K2 + k8 * 16) ^ ((r & 7) << 4);
    *(uint4*)(xlds + byte) = w;
  }
  // stage Wl, Wr (f32 -> bf16)
  for (int c = t; c < 2 * 64 * KC; c += 256) {
    const int m = c / (64 * KC);
    const int c2 = c - m * 64 * KC;
    const int r = c2 / KC, k8 = c2 - r * KC;
    const float4* p = (const float4*)((m ? Wr : Wl) + (size_t)r * K + k8 * 8);
    const float4 f0 = p[0];
    const float4 f1 = p[1];
    uint4 w;
    w.x = pack2(f0.x, f0.y);
    w.y = pack2(f0.z, f0.w);
    w.z = pack2(f1.x, f1.y);
    w.w = pack2(f1.z, f1.w);
    const int byte = (m * 64 * K2) + ((r * K2 + k8 * 16) ^ ((r & 7) << 4));
    *(uint4*)(wlds + byte) = w;
  }
  __syncthreads();

  f32x4 accY[2][4], accZ[2][4];
#pragma unroll
  for (int rt = 0; rt < 2; ++rt)
#pragma unroll
    for (int ct = 0; ct < 4; ++ct) {
      accY[rt][ct] = (f32x4){0.f, 0.f, 0.f, 0.f};
      accZ[rt][ct] = (f32x4){0.f, 0.f, 0.f, 0.f};
    }

  const int fr = lane & 15;
  const int kg = lane >> 4;
#pragma unroll
  for (int kk = 0; kk < K / 32; ++kk) {
    const int kbyte = kk * 64 + kg * 16;
    short8 a[2];
#pragma unroll
    for (int rt = 0; rt < 2; ++rt) {
      const int r = wv * 32 + rt * 16 + fr;
      a[rt] = *(const short8*)(xlds + ((r * K2 + kbyte) ^ ((r & 7) << 4)));
    }
#pragma unroll
    for (int ct = 0; ct < 4; ++ct) {
      const int wr = ct * 16 + fr;
      const int byteY = (wr * K2 + kbyte) ^ ((wr & 7) << 4);
      const short8 bY = *(const short8*)(wlds + byteY);
      const short8 bZ = *(const short8*)(wlds + byteY + 64 * K2);
#pragma unroll
      for (int rt = 0; rt < 2; ++rt) {
        accY[rt][ct] =
            __builtin_amdgcn_mfma_f32_16x16x32_bf16(a[rt], bY, accY[rt][ct], 0, 0, 0);
        accZ[rt][ct] =
            __builtin_amdgcn_mfma_f32_16x16x32_bf16(a[rt], bZ, accZ[rt][ct], 0, 0, 0);
      }
    }
  }

  // epilogue: D row=(lane>>4)*4+q, col=lane&15  [m89-verified]
#pragma unroll
  for (int rt = 0; rt < 2; ++rt) {
#pragma unroll
    for (int q = 0; q < 4; ++q) {
      const int row = rowBase + wv * 32 + rt * 16 + kg * 4 + q;
      if (row < n) {
#pragma unroll
        for (int ct = 0; ct < 4; ++ct) {
          const int col = ct * 16 + fr;
          Y8[(size_t)row * 64 + col] = f2fp8(accY[rt][ct][q]);
          Zb[(size_t)row * 64 + col] = f2bf(accZ[rt][ct][q]);
        }
      }
    }
  }
}

// ---- gather-reduce per node: 16-lane group per edge, uint (4 fp8 ch, 4B) per lane ----
// Lane = g*16 + r (g=edge-stream 0..3, r=channel-slot 0..15). Edge eb+4j+g is read
// at step j from lane g*16+j's csr value. dword loads: 2x the per-instr rate of
// dwordx2 observed in R9 (74 vs 37.5 G edges/s).
template <bool FINAL>
__global__ __launch_bounds__(256) void gather_k(
    const int* __restrict__ noff, const int* __restrict__ csr,
    const uchar_t* __restrict__ Y8, const ushort_t* __restrict__ Zb,
    const float* __restrict__ bias, const float* __restrict__ Wh,
    const float* __restrict__ bh, ushort_t* __restrict__ Hb,
    float* __restrict__ Hf, float* __restrict__ logits, int n) {
  const int lane = threadIdx.x & 63;
  const int g = lane >> 4;  // edge stream 0..3
  const int r = lane & 15;  // channel slot: channels r*4 .. r*4+3
  const int wid = (blockIdx.x * blockDim.x + threadIdx.x) >> 6;
  const int nw = (gridDim.x * blockDim.x) >> 6;
  const float4 b4 = ((const float4*)bias)[r];
  float4 wh4[5];
  if (FINAL) {
#pragma unroll
    for (int o = 0; o < 5; ++o) wh4[o] = ((const float4*)(Wh + o * 64))[r];
  }

  for (int row = wid; row < n; row += nw) {
    const int e0 = noff[row];
    const int e1 = noff[row + 1];
    const int ne = e1 - e0;
    float a0 = 0.f, a1 = 0.f, a2 = 0.f, a3 = 0.f;
    for (int eb = e0; eb < e1; eb += 64) {
      const int eidx = eb + 4 * r + g;  // lane g*16+j holds edge eb+4j+g
      const int sidx = (eidx < e1) ? csr[eidx] : N_NODES;
      const int msteps = min(16, (e1 - eb + 3) >> 2);
      int j = 0;
      for (; j + 3 < msteps; j += 4) {
        const int s0 = __shfl(sidx, j, 16);
        const int s1 = __shfl(sidx, j + 1, 16);
        const int s2 = __shfl(sidx, j + 2, 16);
        const int s3 = __shfl(sidx, j + 3, 16);
        const uint_t v0 = *(const uint_t*)(Y8 + (size_t)s0 * 64 + r * 4);
        const uint_t v1 = *(const uint_t*)(Y8 + (size_t)s1 * 64 + r * 4);
        const uint_t v2 = *(const uint_t*)(Y8 + (size_t)s2 * 64 + r * 4);
        const uint_t v3 = *(const uint_t*)(Y8 + (size_t)s3 * 64 + r * 4);
        fp8x4_acc(v0, a0, a1, a2, a3);
        fp8x4_acc(v1, a0, a1, a2, a3);
        fp8x4_acc(v2, a0, a1, a2, a3);
        fp8x4_acc(v3, a0, a1, a2, a3);
      }
      for (; j < msteps; ++j) {
        const int s0 = __shfl(sidx, j, 16);
        const uint_t v0 = *(const uint_t*)(Y8 + (size_t)s0 * 64 + r * 4);
        fp8x4_acc(v0, a0, a1, a2, a3);
      }
    }
    // combine the 4 edge-streams (xor over g bits: 16, 32)
    a0 += __shfl_xor(a0, 16); a0 += __shfl_xor(a0, 32);
    a1 += __shfl_xor(a1, 16); a1 += __shfl_xor(a1, 32);
    a2 += __shfl_xor(a2, 16); a2 += __shfl_xor(a2, 32);
    a3 += __shfl_xor(a3, 16); a3 += __shfl_xor(a3, 32);

    if (g == 0) {
      const float inv = 1.0f / fmaxf((float)ne, 1.0f);
      const ushort4 zv = *(const ushort4*)(Zb + (size_t)row * 64 + r * 4);
      const float h0 = fmaxf(fmaf(a0, inv, b4.x + bf2f(zv.x)), 0.0f);
      const float h1 = fmaxf(fmaf(a1, inv, b4.y + bf2f(zv.y)), 0.0f);
      const float h2 = fmaxf(fmaf(a2, inv, b4.z + bf2f(zv.z)), 0.0f);
      const float h3 = fmaxf(fmaf(a3, inv, b4.w + bf2f(zv.w)), 0.0f);
      if (!FINAL) {
        ushort4 hb;
        hb.x = f2bf(h0); hb.y = f2bf(h1); hb.z = f2bf(h2); hb.w = f2bf(h3);
        *(ushort4*)(Hb + (size_t)row * 64 + r * 4) = hb;
      } else {
        f32x4 hf = {h0, h1, h2, h3};
        *(f32x4*)(Hf + (size_t)row * 64 + r * 4) = hf;
        float q[5];
#pragma unroll
        for (int o = 0; o < 5; ++o) {
          q[o] = h0 * wh4[o].x + h1 * wh4[o].y + h2 * wh4[o].z + h3 * wh4[o].w;
#pragma unroll
          for (int d = 1; d < 16; d <<= 1) q[o] += __shfl_xor(q[o], d, 16);
        }
        if (r == 0) {
#pragma unroll
          for (int o = 0; o < 5; ++o) logits[(size_t)row * 5 + o] = q[o] + bh[o];
        }
      }
    }
  }
}

extern "C" void kernel_launch(void* const* d_in, const int* in_sizes, int n_in,
                              void* d_out, int out_size, void* d_ws, size_t ws_size,
                              hipStream_t stream) {
  const float* x = (const float*)d_in[0];
  const int* edge = (const int*)d_in[1];
  const float* W1l = (const float*)d_in[2];
  const float* b1l = (const float*)d_in[3];
  const float* W1r = (const float*)d_in[4];
  const float* W2l = (const float*)d_in[5];
  const float* b2l = (const float*)d_in[6];
  const float* W2r = (const float*)d_in[7];
  const float* Wh = (const float*)d_in[8];
  const float* bh = (const float*)d_in[9];
  const int* src = edge;
  const int* dst = edge + N_EDGES;

  float* out = (float*)d_out;
  float* logits = out;                            // [N,5]
  float* hout = out + (size_t)N_NODES * OUT_DIM;  // [N,64] f32

  const size_t N64 = (size_t)N_NODES * 64;
  ushort_t* zb = (ushort_t*)d_ws;          // [N,64] bf16
  ushort_t* h1b = zb + N64;                // [N,64] bf16
  uchar_t* y8 = (uchar_t*)(h1b + N64);     // [N+1,64] fp8 (row N = zeros)
  int* H = (int*)(y8 + N64 + 64);          // [NBUCK][NBF]
  int* P = H + (size_t)NBUCK * NBF;        // [NBUCK][NBF]
  int* bcount = P + (size_t)NBUCK * NBF;   // [NBUCK]
  int* boff = bcount + NBUCK;              // [NBUCK+1]
  int* bedge = boff + NBUCK + 1;           // [E]
  int* csr = bedge + N_EDGES;              // [E]
  int* noff = csr + N_EDGES;               // [N+1]

  // ---- CSR build: deterministic two-phase counting sort (no global atomics) ----
  hipMemsetAsync(y8 + N64, 0, 64, stream);  // zero sentinel row
  histA_k<<<NBF, 256, 0, stream>>>(dst, H);
  colscan_k<<<(NBUCK + 3) / 4, 256, 0, stream>>>(H, P, bcount);
  bscan_k<<<1, 256, 0, stream>>>(bcount, boff, noff);
  fillD_k<<<NBF, 256, 0, stream>>>(src, dst, boff, P, bedge);
  csrfill_k<<<NBUCK, 256, 0, stream>>>(boff, bedge, csr, noff);

  const int mblocks = (N_NODES + 127) / 128;  // 782
  const int wblocks = 6250;                   // 25000 waves, ~4 rows each

  // ---- layer 1 ----
  gemm_mfma<IN_DIM, false><<<mblocks, 256, 0, stream>>>(x, W1l, W1r, y8, zb, N_NODES);
  gather_k<false><<<wblocks, 256, 0, stream>>>(noff, csr, y8, zb, b1l, nullptr,
                                               nullptr, h1b, nullptr, nullptr,
                                               N_NODES);

  // ---- layer 2 + head ----
  gemm_mfma<HID, true><<<mblocks, 256, 0, stream>>>(h1b, W2l, W2r, y8, zb, N_NODES);
  gather_k<true><<<wblocks, 256, 0, stream>>>(noff, csr, y8, zb, b2l, Wh, bh,
                                              nullptr, hout, logits, N_NODES);
}

// Round 15
// 208.211 us; speedup vs baseline: 1.8194x; 1.1419x over previous
//
#include <hip/hip_runtime.h>

#define N_NODES 100000
#define IN_DIM 128
#define HID 64
#define OUT_DIM 5
#define N_EDGES 3200000

#define BSHIFT 7
#define BROWS 128  // nodes per bucket
#define NBUCK ((N_NODES + BROWS - 1) / BROWS)  // 782
#define FILLB_CHUNK 16384
#define NBF ((N_EDGES + FILLB_CHUNK - 1) / FILLB_CHUNK)  // 196

typedef __attribute__((ext_vector_type(8))) short short8;
typedef __attribute__((ext_vector_type(4))) float f32x4;
typedef __attribute__((ext_vector_type(2))) float f32x2_t;
typedef unsigned short ushort_t;
typedef unsigned int uint_t;
typedef unsigned char uchar_t;

static __device__ inline ushort_t f2bf(float f) {
  union { float f; uint_t u; } v; v.f = f;
  const uint_t r = v.u + 0x7FFFu + ((v.u >> 16) & 1u);  // RNE
  return (ushort_t)(r >> 16);
}
static __device__ inline uint_t pack2(float a, float b) {
  return (uint_t)f2bf(a) | ((uint_t)f2bf(b) << 16);
}
static __device__ inline float bf2f(ushort_t u) {
  return __uint_as_float((uint_t)u << 16);
}
// 4 fp8(e4m3) bytes -> accumulate into 4 f32 (HW cvt, 2 per instr)
static __device__ inline void fp8x4_acc(uint_t w, float& c0, float& c1, float& c2,
                                        float& c3) {
  const f32x2_t lo = __builtin_amdgcn_cvt_pk_f32_fp8((int)w, false);
  const f32x2_t hi = __builtin_amdgcn_cvt_pk_f32_fp8((int)w, true);
  c0 += lo[0];
  c1 += lo[1];
  c2 += hi[0];
  c3 += hi[1];
}
static __device__ inline uchar_t f2fp8(float f) {
  return (uchar_t)__builtin_amdgcn_cvt_pk_fp8_f32(f, 0.0f, 0, false);
}

// ---- sort phase A: per-chunk 782-bucket histogram (1024 thr = 16 waves) ----
__global__ __launch_bounds__(1024) void histA_k(const int* __restrict__ dst,
                                                int* __restrict__ H) {
  __shared__ int hist[NBUCK];
  const int t = threadIdx.x;
  const int b = blockIdx.x;
  const int e0 = b * FILLB_CHUNK;
  const int e1 = min(e0 + FILLB_CHUNK, N_EDGES);
  for (int i = t; i < NBUCK; i += 1024) hist[i] = 0;
  __syncthreads();
  for (int e = e0 + t; e < e1; e += 1024) atomicAdd(&hist[dst[e] >> BSHIFT], 1);
  __syncthreads();
  for (int c = t; c < NBUCK; c += 1024) H[(size_t)c * NBF + b] = hist[c];
}

// ---- sort phase A2: per-bucket scan over chunks -> per-(chunk,bucket) bases ----
__global__ __launch_bounds__(256) void colscan_k(const int* __restrict__ H,
                                                 int* __restrict__ P,
                                                 int* __restrict__ bcount) {
  const int lane = threadIdx.x & 63;
  const int wv = threadIdx.x >> 6;
  const int c = blockIdx.x * 4 + wv;
  if (c >= NBUCK) return;
  const int* col = H + (size_t)c * NBF;
  int* pcol = P + (size_t)c * NBF;
  int carry = 0;
#pragma unroll
  for (int k = 0; k < (NBF + 63) / 64; ++k) {
    const int idx = k * 64 + lane;
    const int v = (idx < NBF) ? col[idx] : 0;
    int s = v;
#pragma unroll
    for (int off = 1; off < 64; off <<= 1) {
      const int x = __shfl_up(s, off);
      if (lane >= off) s += x;
    }
    if (idx < NBF) pcol[idx] = carry + s - v;  // exclusive prefix
    carry += __shfl(s, 63);
  }
  if (lane == 0) bcount[c] = carry;
}

// ---- scan: boff[783] (bucket offsets) + noff sentinel ----
__global__ __launch_bounds__(256) void bscan_k(const int* __restrict__ bcount,
                                               int* __restrict__ boff,
                                               int* __restrict__ noff) {
  __shared__ int pref[NBUCK + 1];
  __shared__ int tsum[256];
  const int t = threadIdx.x;
  int v[4];
  int s = 0;
#pragma unroll
  for (int j = 0; j < 4; ++j) {
    const int idx = t * 4 + j;
    v[j] = (idx < NBUCK) ? bcount[idx] : 0;
    s += v[j];
  }
  tsum[t] = s;
  __syncthreads();
  for (int off = 1; off < 256; off <<= 1) {
    int x = (t >= off) ? tsum[t - off] : 0;
    __syncthreads();
    tsum[t] += x;
    __syncthreads();
  }
  int pre = tsum[t] - s;
#pragma unroll
  for (int j = 0; j < 4; ++j) {
    const int idx = t * 4 + j;
    if (idx < NBUCK) pref[idx] = pre;
    pre += v[j];
  }
  if (t == 0) pref[NBUCK] = N_EDGES;
  __syncthreads();
  for (int i = t; i <= NBUCK; i += 256) boff[i] = pref[i];
  if (t == 0) noff[N_NODES] = N_EDGES;
}

// ---- sort phase B: deterministic bucket fill, 16 waves/chunk for latency hiding ----
__global__ __launch_bounds__(1024) void fillD_k(const int* __restrict__ src,
                                                const int* __restrict__ dst,
                                                const int* __restrict__ boff,
                                                const int* __restrict__ P,
                                                int* __restrict__ bedge) {
  __shared__ int base[NBUCK];
  __shared__ int cur[NBUCK];
  const int t = threadIdx.x;
  const int b = blockIdx.x;
  const int e0 = b * FILLB_CHUNK;
  const int e1 = min(e0 + FILLB_CHUNK, N_EDGES);
  for (int c = t; c < NBUCK; c += 1024) {
    base[c] = boff[c] + P[(size_t)c * NBF + b];
    cur[c] = 0;
  }
  __syncthreads();
  for (int e = e0 + t; e < e1; e += 1024) {
    const int d = dst[e];
    const int c = d >> BSHIFT;
    const int pos = base[c] + atomicAdd(&cur[c], 1);
    bedge[pos] = (src[e] << BSHIFT) | (d & (BROWS - 1));
  }
}

// ---- bucket -> full CSR: block per bucket, LDS counting sort ----
__global__ __launch_bounds__(256) void csrfill_k(const int* __restrict__ boff,
                                                 const int* __restrict__ bedge,
                                                 int* __restrict__ csr,
                                                 int* __restrict__ noff) {
  __shared__ int hist[BROWS];
  __shared__ int sc[BROWS];
  __shared__ int cur[BROWS];
  const int t = threadIdx.x;
  const int b = blockIdx.x;
  const int e0 = boff[b];
  const int e1 = boff[b + 1];
  if (t < BROWS) {
    hist[t] = 0;
    cur[t] = 0;
  }
  __syncthreads();
  for (int e = e0 + t; e < e1; e += 256) atomicAdd(&hist[bedge[e] & (BROWS - 1)], 1);
  __syncthreads();
  if (t < BROWS) sc[t] = hist[t];
  __syncthreads();
  for (int off = 1; off < BROWS; off <<= 1) {
    int x = (t >= off && t < BROWS) ? sc[t - off] : 0;
    __syncthreads();
    if (t < BROWS) sc[t] += x;
    __syncthreads();
  }
  if (t < BROWS) {
    const int node = b * BROWS + t;
    if (node < N_NODES) noff[node] = e0 + sc[t] - hist[t];
    sc[t] -= hist[t];
  }
  __syncthreads();
  for (int e = e0 + t; e < e1; e += 256) {
    const int p = bedge[e];
    const int d = p & (BROWS - 1);
    const int pos = e0 + sc[d] + atomicAdd(&cur[d], 1);
    csr[pos] = p >> BSHIFT;
  }
}

// ---- MFMA dual GEMM: Y8 = fp8(X @ Wl^T), Zb = bf16(X @ Wr^T) ----
template <int K, bool BF16IN>
__global__ __launch_bounds__(256) void gemm_mfma(const void* __restrict__ Xv,
                                                 const float* __restrict__ Wl,
                                                 const float* __restrict__ Wr,
                                                 uchar_t* __restrict__ Y8,
                                                 ushort_t* __restrict__ Zb, int n) {
  __shared__ uint4 ldsq[(256 * K * 2) / 16];  // 128 X-rows + 2*64 W-rows, bf16
  char* xlds = (char*)ldsq;
  char* wlds = xlds + 128 * K * 2;
  const int t = threadIdx.x;
  const int lane = t & 63;
  const int wv = t >> 6;
  const int rowBase = blockIdx.x * 128;
  const int K2 = K * 2;
  const int KC = K / 8;  // 16B chunks per row

  // stage X (swizzled)
  for (int c = t; c < 128 * KC; c += 256) {
    const int r = c / KC, k8 = c - r * KC;
    const int row = rowBase + r;
    uint4 w = {0u, 0u, 0u, 0u};
    if (row < n) {
      if (BF16IN) {
        w = ((const uint4*)((const ushort_t*)Xv + (size_t)row * K))[k8];
      } else {
        const float4* p = (const float4*)((const float*)Xv + (size_t)row * K + k8 * 8);
        const float4 f0 = p[0];
        const float4 f1 = p[1];
        w.x = pack2(f0.x, f0.y);
        w.y = pack2(f0.z, f0.w);
        w.z = pack2(f1.x, f1.y);
        w.w = pack2(f1.z, f1.w);
      }
    }
    const int byte = (r * K2 + k8 * 16) ^ ((r & 7) << 4);
    *(uint4*)(xlds + byte) = w;
  }
  // stage Wl, Wr (f32 -> bf16)
  for (int c = t; c < 2 * 64 * KC; c += 256) {
    const int m = c / (64 * KC);
    const int c2 = c - m * 64 * KC;
    const int r = c2 / KC, k8 = c2 - r * KC;
    const float4* p = (const float4*)((m ? Wr : Wl) + (size_t)r * K + k8 * 8);
    const float4 f0 = p[0];
    const float4 f1 = p[1];
    uint4 w;
    w.x = pack2(f0.x, f0.y);
    w.y = pack2(f0.z, f0.w);
    w.z = pack2(f1.x, f1.y);
    w.w = pack2(f1.z, f1.w);
    const int byte = (m * 64 * K2) + ((r * K2 + k8 * 16) ^ ((r & 7) << 4));
    *(uint4*)(wlds + byte) = w;
  }
  __syncthreads();

  f32x4 accY[2][4], accZ[2][4];
#pragma unroll
  for (int rt = 0; rt < 2; ++rt)
#pragma unroll
    for (int ct = 0; ct < 4; ++ct) {
      accY[rt][ct] = (f32x4){0.f, 0.f, 0.f, 0.f};
      accZ[rt][ct] = (f32x4){0.f, 0.f, 0.f, 0.f};
    }

  const int fr = lane & 15;
  const int kg = lane >> 4;
#pragma unroll
  for (int kk = 0; kk < K / 32; ++kk) {
    const int kbyte = kk * 64 + kg * 16;
    short8 a[2];
#pragma unroll
    for (int rt = 0; rt < 2; ++rt) {
      const int r = wv * 32 + rt * 16 + fr;
      a[rt] = *(const short8*)(xlds + ((r * K2 + kbyte) ^ ((r & 7) << 4)));
    }
#pragma unroll
    for (int ct = 0; ct < 4; ++ct) {
      const int wr = ct * 16 + fr;
      const int byteY = (wr * K2 + kbyte) ^ ((wr & 7) << 4);
      const short8 bY = *(const short8*)(wlds + byteY);
      const short8 bZ = *(const short8*)(wlds + byteY + 64 * K2);
#pragma unroll
      for (int rt = 0; rt < 2; ++rt) {
        accY[rt][ct] =
            __builtin_amdgcn_mfma_f32_16x16x32_bf16(a[rt], bY, accY[rt][ct], 0, 0, 0);
        accZ[rt][ct] =
            __builtin_amdgcn_mfma_f32_16x16x32_bf16(a[rt], bZ, accZ[rt][ct], 0, 0, 0);
      }
    }
  }

  // epilogue: D row=(lane>>4)*4+q, col=lane&15  [m89-verified]
#pragma unroll
  for (int rt = 0; rt < 2; ++rt) {
#pragma unroll
    for (int q = 0; q < 4; ++q) {
      const int row = rowBase + wv * 32 + rt * 16 + kg * 4 + q;
      if (row < n) {
#pragma unroll
        for (int ct = 0; ct < 4; ++ct) {
          const int col = ct * 16 + fr;
          Y8[(size_t)row * 64 + col] = f2fp8(accY[rt][ct][q]);
          Zb[(size_t)row * 64 + col] = f2bf(accZ[rt][ct][q]);
        }
      }
    }
  }
}

// ---- gather-reduce per node: 16-lane group per edge, uint (4 fp8 ch, 4B) per lane ----
template <bool FINAL>
__global__ __launch_bounds__(256) void gather_k(
    const int* __restrict__ noff, const int* __restrict__ csr,
    const uchar_t* __restrict__ Y8, const ushort_t* __restrict__ Zb,
    const float* __restrict__ bias, const float* __restrict__ Wh,
    const float* __restrict__ bh, ushort_t* __restrict__ Hb,
    float* __restrict__ Hf, float* __restrict__ logits, int n) {
  const int lane = threadIdx.x & 63;
  const int g = lane >> 4;  // edge stream 0..3
  const int r = lane & 15;  // channel slot: channels r*4 .. r*4+3
  const int wid = (blockIdx.x * blockDim.x + threadIdx.x) >> 6;
  const int nw = (gridDim.x * blockDim.x) >> 6;
  const float4 b4 = ((const float4*)bias)[r];
  float4 wh4[5];
  if (FINAL) {
#pragma unroll
    for (int o = 0; o < 5; ++o) wh4[o] = ((const float4*)(Wh + o * 64))[r];
  }

  for (int row = wid; row < n; row += nw) {
    const int e0 = noff[row];
    const int e1 = noff[row + 1];
    const int ne = e1 - e0;
    float a0 = 0.f, a1 = 0.f, a2 = 0.f, a3 = 0.f;
    for (int eb = e0; eb < e1; eb += 64) {
      const int eidx = eb + 4 * r + g;  // lane g*16+j holds edge eb+4j+g
      const int sidx = (eidx < e1) ? csr[eidx] : N_NODES;
      const int msteps = min(16, (e1 - eb + 3) >> 2);
      int j = 0;
      for (; j + 3 < msteps; j += 4) {
        const int s0 = __shfl(sidx, j, 16);
        const int s1 = __shfl(sidx, j + 1, 16);
        const int s2 = __shfl(sidx, j + 2, 16);
        const int s3 = __shfl(sidx, j + 3, 16);
        const uint_t v0 = *(const uint_t*)(Y8 + (size_t)s0 * 64 + r * 4);
        const uint_t v1 = *(const uint_t*)(Y8 + (size_t)s1 * 64 + r * 4);
        const uint_t v2 = *(const uint_t*)(Y8 + (size_t)s2 * 64 + r * 4);
        const uint_t v3 = *(const uint_t*)(Y8 + (size_t)s3 * 64 + r * 4);
        fp8x4_acc(v0, a0, a1, a2, a3);
        fp8x4_acc(v1, a0, a1, a2, a3);
        fp8x4_acc(v2, a0, a1, a2, a3);
        fp8x4_acc(v3, a0, a1, a2, a3);
      }
      for (; j < msteps; ++j) {
        const int s0 = __shfl(sidx, j, 16);
        const uint_t v0 = *(const uint_t*)(Y8 + (size_t)s0 * 64 + r * 4);
        fp8x4_acc(v0, a0, a1, a2, a3);
      }
    }
    // combine the 4 edge-streams (xor over g bits: 16, 32)
    a0 += __shfl_xor(a0, 16); a0 += __shfl_xor(a0, 32);
    a1 += __shfl_xor(a1, 16); a1 += __shfl_xor(a1, 32);
    a2 += __shfl_xor(a2, 16); a2 += __shfl_xor(a2, 32);
    a3 += __shfl_xor(a3, 16); a3 += __shfl_xor(a3, 32);

    if (g == 0) {
      const float inv = 1.0f / fmaxf((float)ne, 1.0f);
      const ushort4 zv = *(const ushort4*)(Zb + (size_t)row * 64 + r * 4);
      const float h0 = fmaxf(fmaf(a0, inv, b4.x + bf2f(zv.x)), 0.0f);
      const float h1 = fmaxf(fmaf(a1, inv, b4.y + bf2f(zv.y)), 0.0f);
      const float h2 = fmaxf(fmaf(a2, inv, b4.z + bf2f(zv.z)), 0.0f);
      const float h3 = fmaxf(fmaf(a3, inv, b4.w + bf2f(zv.w)), 0.0f);
      if (!FINAL) {
        ushort4 hb;
        hb.x = f2bf(h0); hb.y = f2bf(h1); hb.z = f2bf(h2); hb.w = f2bf(h3);
        *(ushort4*)(Hb + (size_t)row * 64 + r * 4) = hb;
      } else {
        f32x4 hf = {h0, h1, h2, h3};
        *(f32x4*)(Hf + (size_t)row * 64 + r * 4) = hf;
        float q[5];
#pragma unroll
        for (int o = 0; o < 5; ++o) {
          q[o] = h0 * wh4[o].x + h1 * wh4[o].y + h2 * wh4[o].z + h3 * wh4[o].w;
#pragma unroll
          for (int d = 1; d < 16; d <<= 1) q[o] += __shfl_xor(q[o], d, 16);
        }
        if (r == 0) {
#pragma unroll
          for (int o = 0; o < 5; ++o) logits[(size_t)row * 5 + o] = q[o] + bh[o];
        }
      }
    }
  }
}

extern "C" void kernel_launch(void* const* d_in, const int* in_sizes, int n_in,
                              void* d_out, int out_size, void* d_ws, size_t ws_size,
                              hipStream_t stream) {
  const float* x = (const float*)d_in[0];
  const int* edge = (const int*)d_in[1];
  const float* W1l = (const float*)d_in[2];
  const float* b1l = (const float*)d_in[3];
  const float* W1r = (const float*)d_in[4];
  const float* W2l = (const float*)d_in[5];
  const float* b2l = (const float*)d_in[6];
  const float* W2r = (const float*)d_in[7];
  const float* Wh = (const float*)d_in[8];
  const float* bh = (const float*)d_in[9];
  const int* src = edge;
  const int* dst = edge + N_EDGES;

  float* out = (float*)d_out;
  float* logits = out;                            // [N,5]
  float* hout = out + (size_t)N_NODES * OUT_DIM;  // [N,64] f32

  const size_t N64 = (size_t)N_NODES * 64;
  ushort_t* zb = (ushort_t*)d_ws;          // [N,64] bf16
  ushort_t* h1b = zb + N64;                // [N,64] bf16
  uchar_t* y8 = (uchar_t*)(h1b + N64);     // [N+1,64] fp8 (row N = zeros)
  int* H = (int*)(y8 + N64 + 64);          // [NBUCK][NBF]
  int* P = H + (size_t)NBUCK * NBF;        // [NBUCK][NBF]
  int* bcount = P + (size_t)NBUCK * NBF;   // [NBUCK]
  int* boff = bcount + NBUCK;              // [NBUCK+1]
  int* bedge = boff + NBUCK + 1;           // [E]
  int* csr = bedge + N_EDGES;              // [E]
  int* noff = csr + N_EDGES;               // [N+1]

  // ---- CSR build: deterministic two-phase counting sort (no global atomics) ----
  hipMemsetAsync(y8 + N64, 0, 64, stream);  // zero sentinel row
  histA_k<<<NBF, 1024, 0, stream>>>(dst, H);
  colscan_k<<<(NBUCK + 3) / 4, 256, 0, stream>>>(H, P, bcount);
  bscan_k<<<1, 256, 0, stream>>>(bcount, boff, noff);
  fillD_k<<<NBF, 1024, 0, stream>>>(src, dst, boff, P, bedge);
  csrfill_k<<<NBUCK, 256, 0, stream>>>(boff, bedge, csr, noff);

  const int mblocks = (N_NODES + 127) / 128;  // 782
  const int wblocks = 6250;                   // 25000 waves, ~4 rows each

  // ---- layer 1 ----
  gemm_mfma<IN_DIM, false><<<mblocks, 256, 0, stream>>>(x, W1l, W1r, y8, zb, N_NODES);
  gather_k<false><<<wblocks, 256, 0, stream>>>(noff, csr, y8, zb, b1l, nullptr,
                                               nullptr, h1b, nullptr, nullptr,
                                               N_NODES);

  // ---- layer 2 + head ----
  gemm_mfma<HID, true><<<mblocks, 256, 0, stream>>>(h1b, W2l, W2r, y8, zb, N_NODES);
  gather_k<true><<<wblocks, 256, 0, stream>>>(noff, csr, y8, zb, b2l, Wh, bh,
                                              nullptr, hout, logits, N_NODES);
}

// Round 16
// 206.952 us; speedup vs baseline: 1.8305x; 1.0061x over previous
//
#include <hip/hip_runtime.h>

#define N_NODES 100000
#define IN_DIM 128
#define HID 64
#define OUT_DIM 5
#define N_EDGES 3200000

#define BSHIFT 7
#define BROWS 128  // nodes per bucket
#define NBUCK ((N_NODES + BROWS - 1) / BROWS)  // 782
#define FILLB_CHUNK 16384
#define NBF ((N_EDGES + FILLB_CHUNK - 1) / FILLB_CHUNK)  // 196

typedef __attribute__((ext_vector_type(8))) short short8;
typedef __attribute__((ext_vector_type(4))) float f32x4;
typedef __attribute__((ext_vector_type(2))) float f32x2_t;
typedef unsigned short ushort_t;
typedef unsigned int uint_t;
typedef unsigned char uchar_t;

static __device__ inline ushort_t f2bf(float f) {
  union { float f; uint_t u; } v; v.f = f;
  const uint_t r = v.u + 0x7FFFu + ((v.u >> 16) & 1u);  // RNE
  return (ushort_t)(r >> 16);
}
static __device__ inline uint_t pack2(float a, float b) {
  return (uint_t)f2bf(a) | ((uint_t)f2bf(b) << 16);
}
static __device__ inline float bf2f(ushort_t u) {
  return __uint_as_float((uint_t)u << 16);
}
// 4 fp8(e4m3) bytes -> two packed f32x2 accumulators (v_pk_add_f32 path)
static __device__ inline void fp8x4_acc2(uint_t w, f32x2_t& accLo, f32x2_t& accHi) {
  accLo += __builtin_amdgcn_cvt_pk_f32_fp8((int)w, false);
  accHi += __builtin_amdgcn_cvt_pk_f32_fp8((int)w, true);
}
static __device__ inline uchar_t f2fp8(float f) {
  return (uchar_t)__builtin_amdgcn_cvt_pk_fp8_f32(f, 0.0f, 0, false);
}

// ---- sort phase A: per-chunk 782-bucket histogram (1024 thr = 16 waves) ----
__global__ __launch_bounds__(1024) void histA_k(const int* __restrict__ dst,
                                                int* __restrict__ H) {
  __shared__ int hist[NBUCK];
  const int t = threadIdx.x;
  const int b = blockIdx.x;
  const int e0 = b * FILLB_CHUNK;
  const int e1 = min(e0 + FILLB_CHUNK, N_EDGES);
  for (int i = t; i < NBUCK; i += 1024) hist[i] = 0;
  __syncthreads();
  for (int e = e0 + t; e < e1; e += 1024) atomicAdd(&hist[dst[e] >> BSHIFT], 1);
  __syncthreads();
  for (int c = t; c < NBUCK; c += 1024) H[(size_t)c * NBF + b] = hist[c];
}

// ---- sort phase A2: per-bucket scan over chunks -> per-(chunk,bucket) bases ----
__global__ __launch_bounds__(256) void colscan_k(const int* __restrict__ H,
                                                 int* __restrict__ P,
                                                 int* __restrict__ bcount) {
  const int lane = threadIdx.x & 63;
  const int wv = threadIdx.x >> 6;
  const int c = blockIdx.x * 4 + wv;
  if (c >= NBUCK) return;
  const int* col = H + (size_t)c * NBF;
  int* pcol = P + (size_t)c * NBF;
  int carry = 0;
#pragma unroll
  for (int k = 0; k < (NBF + 63) / 64; ++k) {
    const int idx = k * 64 + lane;
    const int v = (idx < NBF) ? col[idx] : 0;
    int s = v;
#pragma unroll
    for (int off = 1; off < 64; off <<= 1) {
      const int x = __shfl_up(s, off);
      if (lane >= off) s += x;
    }
    if (idx < NBF) pcol[idx] = carry + s - v;  // exclusive prefix
    carry += __shfl(s, 63);
  }
  if (lane == 0) bcount[c] = carry;
}

// ---- scan: boff[783] (bucket offsets) + noff sentinel ----
__global__ __launch_bounds__(256) void bscan_k(const int* __restrict__ bcount,
                                               int* __restrict__ boff,
                                               int* __restrict__ noff) {
  __shared__ int pref[NBUCK + 1];
  __shared__ int tsum[256];
  const int t = threadIdx.x;
  int v[4];
  int s = 0;
#pragma unroll
  for (int j = 0; j < 4; ++j) {
    const int idx = t * 4 + j;
    v[j] = (idx < NBUCK) ? bcount[idx] : 0;
    s += v[j];
  }
  tsum[t] = s;
  __syncthreads();
  for (int off = 1; off < 256; off <<= 1) {
    int x = (t >= off) ? tsum[t - off] : 0;
    __syncthreads();
    tsum[t] += x;
    __syncthreads();
  }
  int pre = tsum[t] - s;
#pragma unroll
  for (int j = 0; j < 4; ++j) {
    const int idx = t * 4 + j;
    if (idx < NBUCK) pref[idx] = pre;
    pre += v[j];
  }
  if (t == 0) pref[NBUCK] = N_EDGES;
  __syncthreads();
  for (int i = t; i <= NBUCK; i += 256) boff[i] = pref[i];
  if (t == 0) noff[N_NODES] = N_EDGES;
}

// ---- sort phase B: deterministic bucket fill, 16 waves/chunk ----
__global__ __launch_bounds__(1024) void fillD_k(const int* __restrict__ src,
                                                const int* __restrict__ dst,
                                                const int* __restrict__ boff,
                                                const int* __restrict__ P,
                                                int* __restrict__ bedge) {
  __shared__ int base[NBUCK];
  __shared__ int cur[NBUCK];
  const int t = threadIdx.x;
  const int b = blockIdx.x;
  const int e0 = b * FILLB_CHUNK;
  const int e1 = min(e0 + FILLB_CHUNK, N_EDGES);
  for (int c = t; c < NBUCK; c += 1024) {
    base[c] = boff[c] + P[(size_t)c * NBF + b];
    cur[c] = 0;
  }
  __syncthreads();
  for (int e = e0 + t; e < e1; e += 1024) {
    const int d = dst[e];
    const int c = d >> BSHIFT;
    const int pos = base[c] + atomicAdd(&cur[c], 1);
    bedge[pos] = (src[e] << BSHIFT) | (d & (BROWS - 1));
  }
}

// ---- bucket -> full CSR: block per bucket (16 waves), LDS counting sort ----
__global__ __launch_bounds__(1024) void csrfill_k(const int* __restrict__ boff,
                                                  const int* __restrict__ bedge,
                                                  int* __restrict__ csr,
                                                  int* __restrict__ noff) {
  __shared__ int hist[BROWS];
  __shared__ int sc[BROWS];
  __shared__ int cur[BROWS];
  const int t = threadIdx.x;
  const int b = blockIdx.x;
  const int e0 = boff[b];
  const int e1 = boff[b + 1];
  if (t < BROWS) {
    hist[t] = 0;
    cur[t] = 0;
  }
  __syncthreads();
  for (int e = e0 + t; e < e1; e += 1024) atomicAdd(&hist[bedge[e] & (BROWS - 1)], 1);
  __syncthreads();
  if (t < BROWS) sc[t] = hist[t];
  __syncthreads();
  for (int off = 1; off < BROWS; off <<= 1) {
    int x = (t >= off && t < BROWS) ? sc[t - off] : 0;
    __syncthreads();
    if (t < BROWS) sc[t] += x;
    __syncthreads();
  }
  if (t < BROWS) {
    const int node = b * BROWS + t;
    if (node < N_NODES) noff[node] = e0 + sc[t] - hist[t];
    sc[t] -= hist[t];
  }
  __syncthreads();
  for (int e = e0 + t; e < e1; e += 1024) {
    const int p = bedge[e];
    const int d = p & (BROWS - 1);
    const int pos = e0 + sc[d] + atomicAdd(&cur[d], 1);
    csr[pos] = p >> BSHIFT;
  }
}

// ---- MFMA dual GEMM: Y8 = fp8(X @ Wl^T), Zb = bf16(X @ Wr^T) ----
template <int K, bool BF16IN>
__global__ __launch_bounds__(256) void gemm_mfma(const void* __restrict__ Xv,
                                                 const float* __restrict__ Wl,
                                                 const float* __restrict__ Wr,
                                                 uchar_t* __restrict__ Y8,
                                                 ushort_t* __restrict__ Zb, int n) {
  __shared__ uint4 ldsq[(256 * K * 2) / 16];  // 128 X-rows + 2*64 W-rows, bf16
  char* xlds = (char*)ldsq;
  char* wlds = xlds + 128 * K * 2;
  const int t = threadIdx.x;
  const int lane = t & 63;
  const int wv = t >> 6;
  const int rowBase = blockIdx.x * 128;
  const int K2 = K * 2;
  const int KC = K / 8;  // 16B chunks per row

  // stage X (swizzled)
  for (int c = t; c < 128 * KC; c += 256) {
    const int r = c / KC, k8 = c - r * KC;
    const int row = rowBase + r;
    uint4 w = {0u, 0u, 0u, 0u};
    if (row < n) {
      if (BF16IN) {
        w = ((const uint4*)((const ushort_t*)Xv + (size_t)row * K))[k8];
      } else {
        const float4* p = (const float4*)((const float*)Xv + (size_t)row * K + k8 * 8);
        const float4 f0 = p[0];
        const float4 f1 = p[1];
        w.x = pack2(f0.x, f0.y);
        w.y = pack2(f0.z, f0.w);
        w.z = pack2(f1.x, f1.y);
        w.w = pack2(f1.z, f1.w);
      }
    }
    const int byte = (r * K2 + k8 * 16) ^ ((r & 7) << 4);
    *(uint4*)(xlds + byte) = w;
  }
  // stage Wl, Wr (f32 -> bf16)
  for (int c = t; c < 2 * 64 * KC; c += 256) {
    const int m = c / (64 * KC);
    const int c2 = c - m * 64 * KC;
    const int r = c2 / KC, k8 = c2 - r * KC;
    const float4* p = (const float4*)((m ? Wr : Wl) + (size_t)r * K + k8 * 8);
    const float4 f0 = p[0];
    const float4 f1 = p[1];
    uint4 w;
    w.x = pack2(f0.x, f0.y);
    w.y = pack2(f0.z, f0.w);
    w.z = pack2(f1.x, f1.y);
    w.w = pack2(f1.z, f1.w);
    const int byte = (m * 64 * K2) + ((r * K2 + k8 * 16) ^ ((r & 7) << 4));
    *(uint4*)(wlds + byte) = w;
  }
  __syncthreads();

  f32x4 accY[2][4], accZ[2][4];
#pragma unroll
  for (int rt = 0; rt < 2; ++rt)
#pragma unroll
    for (int ct = 0; ct < 4; ++ct) {
      accY[rt][ct] = (f32x4){0.f, 0.f, 0.f, 0.f};
      accZ[rt][ct] = (f32x4){0.f, 0.f, 0.f, 0.f};
    }

  const int fr = lane & 15;
  const int kg = lane >> 4;
#pragma unroll
  for (int kk = 0; kk < K / 32; ++kk) {
    const int kbyte = kk * 64 + kg * 16;
    short8 a[2];
#pragma unroll
    for (int rt = 0; rt < 2; ++rt) {
      const int r = wv * 32 + rt * 16 + fr;
      a[rt] = *(const short8*)(xlds + ((r * K2 + kbyte) ^ ((r & 7) << 4)));
    }
#pragma unroll
    for (int ct = 0; ct < 4; ++ct) {
      const int wr = ct * 16 + fr;
      const int byteY = (wr * K2 + kbyte) ^ ((wr & 7) << 4);
      const short8 bY = *(const short8*)(wlds + byteY);
      const short8 bZ = *(const short8*)(wlds + byteY + 64 * K2);
#pragma unroll
      for (int rt = 0; rt < 2; ++rt) {
        accY[rt][ct] =
            __builtin_amdgcn_mfma_f32_16x16x32_bf16(a[rt], bY, accY[rt][ct], 0, 0, 0);
        accZ[rt][ct] =
            __builtin_amdgcn_mfma_f32_16x16x32_bf16(a[rt], bZ, accZ[rt][ct], 0, 0, 0);
      }
    }
  }

  // epilogue: D row=(lane>>4)*4+q, col=lane&15  [m89-verified]
#pragma unroll
  for (int rt = 0; rt < 2; ++rt) {
#pragma unroll
    for (int q = 0; q < 4; ++q) {
      const int row = rowBase + wv * 32 + rt * 16 + kg * 4 + q;
      if (row < n) {
#pragma unroll
        for (int ct = 0; ct < 4; ++ct) {
          const int col = ct * 16 + fr;
          Y8[(size_t)row * 64 + col] = f2fp8(accY[rt][ct][q]);
          Zb[(size_t)row * 64 + col] = f2bf(accZ[rt][ct][q]);
        }
      }
    }
  }
}

// ---- gather-reduce per node: 16-lane group per edge, uint (4 fp8 ch, 4B) per lane ----
// Packed f32x2 accumulation (v_pk_add_f32): 2 cvt + 2 pk_add per edge.
template <bool FINAL>
__global__ __launch_bounds__(256) void gather_k(
    const int* __restrict__ noff, const int* __restrict__ csr,
    const uchar_t* __restrict__ Y8, const ushort_t* __restrict__ Zb,
    const float* __restrict__ bias, const float* __restrict__ Wh,
    const float* __restrict__ bh, ushort_t* __restrict__ Hb,
    float* __restrict__ Hf, float* __restrict__ logits, int n) {
  const int lane = threadIdx.x & 63;
  const int g = lane >> 4;  // edge stream 0..3
  const int r = lane & 15;  // channel slot: channels r*4 .. r*4+3
  const int wid = (blockIdx.x * blockDim.x + threadIdx.x) >> 6;
  const int nw = (gridDim.x * blockDim.x) >> 6;
  const float4 b4 = ((const float4*)bias)[r];
  float4 wh4[5];
  if (FINAL) {
#pragma unroll
    for (int o = 0; o < 5; ++o) wh4[o] = ((const float4*)(Wh + o * 64))[r];
  }

  for (int row = wid; row < n; row += nw) {
    const int e0 = noff[row];
    const int e1 = noff[row + 1];
    const int ne = e1 - e0;
    f32x2_t aLo = {0.f, 0.f}, aHi = {0.f, 0.f};
    for (int eb = e0; eb < e1; eb += 64) {
      const int eidx = eb + 4 * r + g;  // lane g*16+j holds edge eb+4j+g
      const int sidx = (eidx < e1) ? csr[eidx] : N_NODES;
      const int msteps = min(16, (e1 - eb + 3) >> 2);
      int j = 0;
      for (; j + 3 < msteps; j += 4) {
        const int s0 = __shfl(sidx, j, 16);
        const int s1 = __shfl(sidx, j + 1, 16);
        const int s2 = __shfl(sidx, j + 2, 16);
        const int s3 = __shfl(sidx, j + 3, 16);
        const uint_t v0 = *(const uint_t*)(Y8 + (size_t)s0 * 64 + r * 4);
        const uint_t v1 = *(const uint_t*)(Y8 + (size_t)s1 * 64 + r * 4);
        const uint_t v2 = *(const uint_t*)(Y8 + (size_t)s2 * 64 + r * 4);
        const uint_t v3 = *(const uint_t*)(Y8 + (size_t)s3 * 64 + r * 4);
        fp8x4_acc2(v0, aLo, aHi);
        fp8x4_acc2(v1, aLo, aHi);
        fp8x4_acc2(v2, aLo, aHi);
        fp8x4_acc2(v3, aLo, aHi);
      }
      for (; j < msteps; ++j) {
        const int s0 = __shfl(sidx, j, 16);
        const uint_t v0 = *(const uint_t*)(Y8 + (size_t)s0 * 64 + r * 4);
        fp8x4_acc2(v0, aLo, aHi);
      }
    }
    float a0 = aLo[0], a1 = aLo[1], a2 = aHi[0], a3 = aHi[1];
    // combine the 4 edge-streams (xor over g bits: 16, 32)
    a0 += __shfl_xor(a0, 16); a0 += __shfl_xor(a0, 32);
    a1 += __shfl_xor(a1, 16); a1 += __shfl_xor(a1, 32);
    a2 += __shfl_xor(a2, 16); a2 += __shfl_xor(a2, 32);
    a3 += __shfl_xor(a3, 16); a3 += __shfl_xor(a3, 32);

    if (g == 0) {
      const float inv = 1.0f / fmaxf((float)ne, 1.0f);
      const ushort4 zv = *(const ushort4*)(Zb + (size_t)row * 64 + r * 4);
      const float h0 = fmaxf(fmaf(a0, inv, b4.x + bf2f(zv.x)), 0.0f);
      const float h1 = fmaxf(fmaf(a1, inv, b4.y + bf2f(zv.y)), 0.0f);
      const float h2 = fmaxf(fmaf(a2, inv, b4.z + bf2f(zv.z)), 0.0f);
      const float h3 = fmaxf(fmaf(a3, inv, b4.w + bf2f(zv.w)), 0.0f);
      if (!FINAL) {
        ushort4 hb;
        hb.x = f2bf(h0); hb.y = f2bf(h1); hb.z = f2bf(h2); hb.w = f2bf(h3);
        *(ushort4*)(Hb + (size_t)row * 64 + r * 4) = hb;
      } else {
        f32x4 hf = {h0, h1, h2, h3};
        *(f32x4*)(Hf + (size_t)row * 64 + r * 4) = hf;
        float q[5];
#pragma unroll
        for (int o = 0; o < 5; ++o) {
          q[o] = h0 * wh4[o].x + h1 * wh4[o].y + h2 * wh4[o].z + h3 * wh4[o].w;
#pragma unroll
          for (int d = 1; d < 16; d <<= 1) q[o] += __shfl_xor(q[o], d, 16);
        }
        if (r == 0) {
#pragma unroll
          for (int o = 0; o < 5; ++o) logits[(size_t)row * 5 + o] = q[o] + bh[o];
        }
      }
    }
  }
}

extern "C" void kernel_launch(void* const* d_in, const int* in_sizes, int n_in,
                              void* d_out, int out_size, void* d_ws, size_t ws_size,
                              hipStream_t stream) {
  const float* x = (const float*)d_in[0];
  const int* edge = (const int*)d_in[1];
  const float* W1l = (const float*)d_in[2];
  const float* b1l = (const float*)d_in[3];
  const float* W1r = (const float*)d_in[4];
  const float* W2l = (const float*)d_in[5];
  const float* b2l = (const float*)d_in[6];
  const float* W2r = (const float*)d_in[7];
  const float* Wh = (const float*)d_in[8];
  const float* bh = (const float*)d_in[9];
  const int* src = edge;
  const int* dst = edge + N_EDGES;

  float* out = (float*)d_out;
  float* logits = out;                            // [N,5]
  float* hout = out + (size_t)N_NODES * OUT_DIM;  // [N,64] f32

  const size_t N64 = (size_t)N_NODES * 64;
  ushort_t* zb = (ushort_t*)d_ws;          // [N,64] bf16
  ushort_t* h1b = zb + N64;                // [N,64] bf16
  uchar_t* y8 = (uchar_t*)(h1b + N64);     // [N+1,64] fp8 (row N = zeros)
  int* H = (int*)(y8 + N64 + 64);          // [NBUCK][NBF]
  int* P = H + (size_t)NBUCK * NBF;        // [NBUCK][NBF]
  int* bcount = P + (size_t)NBUCK * NBF;   // [NBUCK]
  int* boff = bcount + NBUCK;              // [NBUCK+1]
  int* bedge = boff + NBUCK + 1;           // [E]
  int* csr = bedge + N_EDGES;              // [E]
  int* noff = csr + N_EDGES;               // [N+1]

  // ---- CSR build: deterministic two-phase counting sort (no global atomics) ----
  hipMemsetAsync(y8 + N64, 0, 64, stream);  // zero sentinel row
  histA_k<<<NBF, 1024, 0, stream>>>(dst, H);
  colscan_k<<<(NBUCK + 3) / 4, 256, 0, stream>>>(H, P, bcount);
  bscan_k<<<1, 256, 0, stream>>>(bcount, boff, noff);
  fillD_k<<<NBF, 1024, 0, stream>>>(src, dst, boff, P, bedge);
  csrfill_k<<<NBUCK, 1024, 0, stream>>>(boff, bedge, csr, noff);

  const int mblocks = (N_NODES + 127) / 128;  // 782
  const int wblocks = 6250;                   // 25000 waves, ~4 rows each

  // ---- layer 1 ----
  gemm_mfma<IN_DIM, false><<<mblocks, 256, 0, stream>>>(x, W1l, W1r, y8, zb, N_NODES);
  gather_k<false><<<wblocks, 256, 0, stream>>>(noff, csr, y8, zb, b1l, nullptr,
                                               nullptr, h1b, nullptr, nullptr,
                                               N_NODES);

  // ---- layer 2 + head ----
  gemm_mfma<HID, true><<<mblocks, 256, 0, stream>>>(h1b, W2l, W2r, y8, zb, N_NODES);
  gather_k<true><<<wblocks, 256, 0, stream>>>(noff, csr, y8, zb, b2l, Wh, bh,
                                              nullptr, hout, logits, N_NODES);
}